// Round 3
// baseline (528.528 us; speedup 1.0000x reference)
//
#include <hip/hip_runtime.h>
#include <hip/hip_bf16.h>
#include <math.h>

#define N_USERS 100000
#define N_ITEMS 50000
#define N_EDGES 2000000
#define D 64

// Coarse bins: 512 nodes per bin (binfill write-coalescing granularity).
#define FB_BINS 98                    // ceil(50000/512)  forward (by item)
#define BB_BINS 196                   // ceil(100000/512) backward (by user)
#define NBINS   (FB_BINS + BB_BINS)   // 294
#define NBINS_P8 296                  // padded multiple-of-8 for redist quad map
#define CHUNK   2048                  // edges per binfill WG
#define NCHUNK  ((N_EDGES + CHUNK - 1) / CHUNK)   // 977
// Fine id space: items at [0, 50176) (512-padded), users at [50176, 150528).
#define FINE_FWD (FB_BINS * 512)      // 50176
#define FINE_TOT (NBINS * 512)        // 150528
#define SCAN_BLK 4096
#define SCAN_WGS 37                   // 37 * 4096 = 151552 >= FINE_TOT
#define FINE_PAD (SCAN_WGS * SCAN_BLK)
#define TOTSLOT  (2 * N_EDGES)        // 4M stage/stage2 entries
// pass2: 256-thread WGs, 4 waves, 8 nodes per wave = 32 nodes per WG.
#define FWD_WGS ((N_ITEMS + 31) / 32) // 1563
#define BWD_WGS ((N_USERS + 31) / 32) // 3125

// ---- bf16 pack/unpack helpers --------------------------------------------
__device__ __forceinline__ float blo(unsigned u) {
    union { unsigned i; float f; } c; c.i = u << 16; return c.f;
}
__device__ __forceinline__ float bhi(unsigned u) {
    union { unsigned i; float f; } c; c.i = u & 0xFFFF0000u; return c.f;
}
__device__ __forceinline__ unsigned bpack(float x, float y) {
    __hip_bfloat16 a = __float2bfloat16(x), b = __float2bfloat16(y);
    unsigned short ua = *reinterpret_cast<unsigned short*>(&a);
    unsigned short ub = *reinterpret_cast<unsigned short*>(&b);
    return (unsigned)ua | ((unsigned)ub << 16);
}

// ---------------------------------------------------------------------------
// prep: fused h2b (fp32 -> packed bf16 pairs) + fine degree histogram from the
// raw edge list (fire-and-forget global atomics into the 600 KB deg array).
// ---------------------------------------------------------------------------
__global__ __launch_bounds__(256) void prep_kernel(
    const float2* __restrict__ hin, unsigned* __restrict__ hu16,
    const int* __restrict__ src, const int* __restrict__ dst,
    int* __restrict__ deg) {
    int stride = gridDim.x * blockDim.x;
    int t0 = blockIdx.x * blockDim.x + threadIdx.x;
    for (int i = t0; i < N_USERS * 32; i += stride) {
        float2 v = hin[i];
        hu16[i] = bpack(v.x, v.y);
    }
    for (int e = t0; e < N_EDGES; e += stride) {
        atomicAdd(&deg[dst[e]], 1);
        atomicAdd(&deg[FINE_FWD + src[e]], 1);
    }
}

// ---------------------------------------------------------------------------
// scanA: per-4096-block totals of deg (37 WGs).
// ---------------------------------------------------------------------------
__global__ __launch_bounds__(256) void scanA_kernel(
    const int* __restrict__ deg, int* __restrict__ blocksum) {
    __shared__ int ws[4];
    int b = blockIdx.x, t = threadIdx.x, lane = t & 63, wv = t >> 6;
    const int4* Dp = (const int4*)(deg + b * SCAN_BLK);
    int s = 0;
#pragma unroll
    for (int j = 0; j < 4; j++) {
        int4 v = Dp[t * 4 + j];
        s += v.x + v.y + v.z + v.w;
    }
#pragma unroll
    for (int off = 32; off; off >>= 1) s += __shfl_xor(s, off);
    if (lane == 0) ws[wv] = s;
    __syncthreads();
    if (t == 0) blocksum[b] = ws[0] + ws[1] + ws[2] + ws[3];
}

// ---------------------------------------------------------------------------
// scanB: block 0 = exclusive scan of the 37 block sums; block 1 = softmax
// stats over edge_w (stats[0]=max, stats[1]=sum(exp(x-max))).
// ---------------------------------------------------------------------------
__global__ void scanB_kernel(const int* __restrict__ blocksum, int* __restrict__ blockbase,
                             const float* __restrict__ w, float* __restrict__ stats) {
    __shared__ float red[16];
    if (blockIdx.x == 0) {
        int t = threadIdx.x;
        if (t < 64) {
            int v = (t < SCAN_WGS) ? blocksum[t] : 0;
            int incl = v;
#pragma unroll
            for (int off = 1; off < 64; off <<= 1) {
                int u = __shfl_up(incl, off);
                if (t >= off) incl += u;
            }
            if (t < SCAN_WGS) blockbase[t] = incl - v;
        }
        return;
    }
    int tid = threadIdx.x, lane = tid & 63, wid = tid >> 6;

    float m = -INFINITY;
    for (int i = tid; i < N_ITEMS; i += 1024) m = fmaxf(m, w[i]);
#pragma unroll
    for (int off = 32; off; off >>= 1) m = fmaxf(m, __shfl_xor(m, off));
    if (lane == 0) red[wid] = m;
    __syncthreads();
    if (tid == 0) {
        float t = red[0];
        for (int k = 1; k < 16; k++) t = fmaxf(t, red[k]);
        red[0] = t;
    }
    __syncthreads();
    m = red[0];
    __syncthreads();

    float s = 0.f;
    for (int i = tid; i < N_ITEMS; i += 1024) s += expf(w[i] - m);
#pragma unroll
    for (int off = 32; off; off >>= 1) s += __shfl_xor(s, off);
    if (lane == 0) red[wid] = s;
    __syncthreads();
    if (tid == 0) {
        float t = 0.f;
        for (int k = 0; k < 16; k++) t += red[k];
        stats[0] = m;
        stats[1] = t;
    }
}

// ---------------------------------------------------------------------------
// scanC: final exclusive scan. Writes fineoff, the running cursor (in-place
// over deg), and the coarse binfill cursors gcur[B] = fineoff[512B].
// ---------------------------------------------------------------------------
__global__ __launch_bounds__(256) void scanC_kernel(
    const int* __restrict__ blockbase, int* deg_cur,
    int* __restrict__ fineoff, int* __restrict__ gcur) {
    __shared__ int wbase[4];
    int b = blockIdx.x, t = threadIdx.x, lane = t & 63, wv = t >> 6;
    int4 v[4];
    const int4* Dp = (const int4*)(deg_cur + b * SCAN_BLK);
#pragma unroll
    for (int j = 0; j < 4; j++) v[j] = Dp[t * 4 + j];
    int tot = 0;
#pragma unroll
    for (int j = 0; j < 4; j++) tot += v[j].x + v[j].y + v[j].z + v[j].w;
    int incl = tot;
#pragma unroll
    for (int off = 1; off < 64; off <<= 1) {
        int u = __shfl_up(incl, off);
        if (lane >= off) incl += u;
    }
    if (lane == 63) wbase[wv] = incl;
    __syncthreads();
    if (t == 0) {
        int run = 0;
#pragma unroll
        for (int k = 0; k < 4; k++) { int x = wbase[k]; wbase[k] = run; run += x; }
    }
    __syncthreads();
    int base = blockbase[b] + wbase[wv] + incl - tot;
    int idx0 = b * SCAN_BLK + t * 16;
#pragma unroll
    for (int j = 0; j < 4; j++) {
        int c0 = v[j].x, c1 = v[j].y, c2 = v[j].z, c3 = v[j].w;
        int i = idx0 + j * 4;
        fineoff[i] = base; deg_cur[i] = base;
        if ((i & 511) == 0 && (i >> 9) < NBINS) gcur[i >> 9] = base;
        base += c0;
        fineoff[i + 1] = base; deg_cur[i + 1] = base; base += c1;
        fineoff[i + 2] = base; deg_cur[i + 2] = base; base += c2;
        fineoff[i + 3] = base; deg_cur[i + 3] = base; base += c3;
    }
}

// ---------------------------------------------------------------------------
// binfill: chunk-aggregated scatter into coarse bins (dense ~56 B runs).
// fwd entry: s(17b) | d_local9<<17 ; bwd entry: d(16b) | s_local9<<16.
// ---------------------------------------------------------------------------
__global__ __launch_bounds__(256) void binfill_kernel(
    const int* __restrict__ src, const int* __restrict__ dst,
    int* __restrict__ gcur, unsigned* __restrict__ stage) {
    __shared__ int cnt[NBINS];
    __shared__ int gbase[NBINS];
    __shared__ int lcur[NBINS];
    int c = blockIdx.x;
    int base = c * CHUNK;
    int nEdge = N_EDGES - base; if (nEdge > CHUNK) nEdge = CHUNK;

    for (int t = threadIdx.x; t < NBINS; t += 256) { cnt[t] = 0; lcur[t] = 0; }
    __syncthreads();

    int es[8], ed[8];
#pragma unroll
    for (int j = 0; j < 8; j++) {
        int k = j * 256 + threadIdx.x;
        if (k < nEdge) {
            es[j] = src[base + k];
            ed[j] = dst[base + k];
            atomicAdd(&cnt[ed[j] >> 9], 1);
            atomicAdd(&cnt[FB_BINS + (es[j] >> 9)], 1);
        } else {
            es[j] = -1;
        }
    }
    __syncthreads();
    for (int t = threadIdx.x; t < NBINS; t += 256) {
        int cv = cnt[t];
        gbase[t] = cv ? atomicAdd(&gcur[t], cv) : 0;
    }
    __syncthreads();
#pragma unroll
    for (int j = 0; j < 8; j++) {
        if (es[j] >= 0) {
            int s = es[j], d = ed[j];
            int bf = d >> 9;
            int p = atomicAdd(&lcur[bf], 1);
            stage[gbase[bf] + p] = (unsigned)s | ((unsigned)(d & 511) << 17);
            int bb = FB_BINS + (s >> 9);
            int q = atomicAdd(&lcur[bb], 1);
            stage[gbase[bb] + q] = (unsigned)d | ((unsigned)(s & 511) << 16);
        }
    }
}

// ---------------------------------------------------------------------------
// redist2: scatter-only fine sort. One quarter-bin per WG; global fine
// cursors (cur, pre-initialized = fineoff by scanC). x%296 mapping keeps all
// 4 sub-WGs of a bin on one XCD so bin-local stage2 lines stay in one L2.
// ---------------------------------------------------------------------------
__global__ __launch_bounds__(256) void redist2_kernel(
    const unsigned* __restrict__ stage, const int* __restrict__ fineoff,
    int* __restrict__ cur, unsigned* __restrict__ stage2) {
    int x = blockIdx.x;
    int B = x % NBINS_P8, s4 = x / NBINS_P8;
    if (B >= NBINS) return;
    int beg = fineoff[B << 9], end = fineoff[(B + 1) << 9];
    int n = end - beg;
    int q0 = beg + ((n * s4) >> 2), q1 = beg + ((n * (s4 + 1)) >> 2);
    int t = threadIdx.x;
    if (B < FB_BINS) {
        for (int k = q0 + t; k < q1; k += 256) {
            unsigned e = stage[k];
            int gid = (B << 9) | (int)(e >> 17);
            int p = atomicAdd(&cur[gid], 1);
            stage2[p] = e & 0x1FFFFu;
        }
    } else {
        for (int k = q0 + t; k < q1; k += 256) {
            unsigned e = stage[k];
            int gid = (B << 9) | (int)(e >> 16);   // B<<9 == FINE_FWD + (B-98)*512
            int p = atomicAdd(&cur[gid], 1);
            stage2[p] = e & 0xFFFFu;
        }
    }
}

// ---------------------------------------------------------------------------
// pass2 fwd: pure gather. 256 threads = 4 waves; each wave owns 8 items.
// Per item: read its contiguous fine edge slice, gather bf16 h_user rows
// (half-wave per edge, uint = 2 bf16 feats/lane), fused epilogue, bf16 out.
// ---------------------------------------------------------------------------
__global__ __launch_bounds__(256) void pass2_fwd_kernel(
    const unsigned* __restrict__ hu16, const float* __restrict__ pf,
    const float* __restrict__ edge_w, const unsigned* __restrict__ stage2,
    const int* __restrict__ fineoff, const float* __restrict__ stats,
    unsigned* __restrict__ rst16) {
    int tid = threadIdx.x, lane = tid & 63, wv = tid >> 6;
    int q = lane & 31, half = lane >> 5;
    float m = stats[0], ssum = stats[1];
    const float2* PF2 = (const float2*)pf;
    int i0 = blockIdx.x * 32;

    for (int il = wv; il < 32; il += 4) {
        int i = i0 + il;
        if (i >= N_ITEMS) break;
        int a = fineoff[i], b = fineoff[i + 1];
        float ax = 0.f, ay = 0.f;
        int k = a;
        for (; k + 8 <= b; k += 8) {
            int s0 = (int)stage2[k + half],     s1 = (int)stage2[k + 2 + half];
            int s2 = (int)stage2[k + 4 + half], s3 = (int)stage2[k + 6 + half];
            unsigned u0 = hu16[(s0 << 5) + q];
            unsigned u1 = hu16[(s1 << 5) + q];
            unsigned u2 = hu16[(s2 << 5) + q];
            unsigned u3 = hu16[(s3 << 5) + q];
            ax += (blo(u0) + blo(u1)) + (blo(u2) + blo(u3));
            ay += (bhi(u0) + bhi(u1)) + (bhi(u2) + bhi(u3));
        }
        for (; k + 2 <= b; k += 2) {
            unsigned u = hu16[((int)stage2[k + half] << 5) + q];
            ax += blo(u); ay += bhi(u);
        }
        if (k < b && half == 0) {
            unsigned u = hu16[((int)stage2[k] << 5) + q];
            ax += blo(u); ay += bhi(u);
        }
        ax += __shfl_xor(ax, 32);
        ay += __shfl_xor(ay, 32);
        if (half == 0) {
            float deg = (float)(b - a);
            if (deg < 1.f) deg = 1.f;
            float sc = expf(edge_w[i] - m) / (ssum * deg);
            float2 pv = PF2[(size_t)i * 32 + q];
            float vx = (ax + 0.5f * tanhf(pv.x)) * sc;
            float vy = (ay + 0.5f * tanhf(pv.y)) * sc;
            rst16[(size_t)i * 32 + q] = bpack(vx, vy);
        }
    }
}

// ---------------------------------------------------------------------------
// pass2 bwd: same pure-gather plan over bf16 rst; fp32 output with deg norm.
// ---------------------------------------------------------------------------
__global__ __launch_bounds__(256) void pass2_bwd_kernel(
    const unsigned* __restrict__ rst16, const unsigned* __restrict__ stage2,
    const int* __restrict__ fineoff, float* __restrict__ out) {
    int tid = threadIdx.x, lane = tid & 63, wv = tid >> 6;
    int q = lane & 31, half = lane >> 5;
    float2* OUT2 = (float2*)out;
    int u0i = blockIdx.x * 32;

    for (int il = wv; il < 32; il += 4) {
        int u = u0i + il;
        if (u >= N_USERS) break;
        int a = fineoff[FINE_FWD + u], b = fineoff[FINE_FWD + u + 1];
        float ax = 0.f, ay = 0.f;
        int k = a;
        for (; k + 8 <= b; k += 8) {
            int d0 = (int)stage2[k + half],     d1 = (int)stage2[k + 2 + half];
            int d2 = (int)stage2[k + 4 + half], d3 = (int)stage2[k + 6 + half];
            unsigned u0 = rst16[(d0 << 5) + q];
            unsigned u1 = rst16[(d1 << 5) + q];
            unsigned u2 = rst16[(d2 << 5) + q];
            unsigned u3 = rst16[(d3 << 5) + q];
            ax += (blo(u0) + blo(u1)) + (blo(u2) + blo(u3));
            ay += (bhi(u0) + bhi(u1)) + (bhi(u2) + bhi(u3));
        }
        for (; k + 2 <= b; k += 2) {
            unsigned e = rst16[((int)stage2[k + half] << 5) + q];
            ax += blo(e); ay += bhi(e);
        }
        if (k < b && half == 0) {
            unsigned e = rst16[((int)stage2[k] << 5) + q];
            ax += blo(e); ay += bhi(e);
        }
        ax += __shfl_xor(ax, 32);
        ay += __shfl_xor(ay, 32);
        if (half == 0) {
            float deg = (float)(b - a);
            if (deg < 1.f) deg = 1.f;
            OUT2[(size_t)u * 32 + q] = make_float2(ax / deg, ay / deg);
        }
    }
}

// ---------------------------------------------------------------------------
extern "C" void kernel_launch(void* const* d_in, const int* in_sizes, int n_in,
                              void* d_out, int out_size, void* d_ws, size_t ws_size,
                              hipStream_t stream) {
    const float* h_user = (const float*)d_in[0];   // [N_USERS, D]
    const float* pf     = (const float*)d_in[1];   // [N_ITEMS, D]
    const float* edge_w = (const float*)d_in[2];   // [N_ITEMS]
    const int*   src    = (const int*)d_in[3];     // [N_EDGES]
    const int*   dst    = (const int*)d_in[4];     // [N_EDGES]
    float* out = (float*)d_out;                    // [N_USERS, D]

    // workspace carve-up (~53 MB)
    char* p = (char*)d_ws;
    int* deg      = (int*)p;     p += sizeof(int) * FINE_PAD;   // doubles as cur
    int* fineoff  = (int*)p;     p += sizeof(int) * FINE_PAD;
    int* gcur     = (int*)p;     p += sizeof(int) * NBINS_P8;
    int* blocksum = (int*)p;     p += sizeof(int) * 64;
    int* blockbase= (int*)p;     p += sizeof(int) * 64;
    unsigned* stage  = (unsigned*)p; p += sizeof(unsigned) * (size_t)TOTSLOT;
    unsigned* stage2 = (unsigned*)p; p += sizeof(unsigned) * (size_t)TOTSLOT;
    unsigned* hu16   = (unsigned*)p; p += sizeof(unsigned) * (size_t)N_USERS * 32;
    unsigned* rst16  = (unsigned*)p; p += sizeof(unsigned) * (size_t)N_ITEMS * 32;
    float* stats = (float*)p;    p += 4 * sizeof(float);

    hipMemsetAsync(deg, 0, sizeof(int) * FINE_PAD, stream);

    prep_kernel<<<1024, 256, 0, stream>>>((const float2*)h_user, hu16, src, dst, deg);
    scanA_kernel<<<SCAN_WGS, 256, 0, stream>>>(deg, blocksum);
    scanB_kernel<<<2, 1024, 0, stream>>>(blocksum, blockbase, edge_w, stats);
    scanC_kernel<<<SCAN_WGS, 256, 0, stream>>>(blockbase, deg, fineoff, gcur);
    binfill_kernel<<<NCHUNK, 256, 0, stream>>>(src, dst, gcur, stage);
    redist2_kernel<<<4 * NBINS_P8, 256, 0, stream>>>(stage, fineoff, deg, stage2);
    pass2_fwd_kernel<<<FWD_WGS, 256, 0, stream>>>(hu16, pf, edge_w, stage2, fineoff, stats, rst16);
    pass2_bwd_kernel<<<BWD_WGS, 256, 0, stream>>>(rst16, stage2, fineoff, out);
}

// Round 4
// 398.087 us; speedup vs baseline: 1.3277x; 1.3277x over previous
//
#include <hip/hip_runtime.h>
#include <hip/hip_bf16.h>
#include <math.h>

#define N_USERS 100000
#define N_ITEMS 50000
#define N_EDGES 2000000
#define D 64

// Coarse bins: 512 nodes per bin (binfill write-coalescing granularity).
#define FB_BINS 98                    // ceil(50000/512)  forward (by item)
#define BB_BINS 196                   // ceil(100000/512) backward (by user)
#define NBINS   (FB_BINS + BB_BINS)   // 294
#define CHUNK   2048                  // edges per binfill WG
#define NCHUNK  ((N_EDGES + CHUNK - 1) / CHUNK)   // 977
#define NSH     4                     // user shards for fwd gather (3.2MB hu16 slice/shard)
// fwd fine space: (item, shard). foff_f[i*4+s] -> start of slice in stage2.
#define FOFF_F_N (FB_BINS * 512 * NSH + 1)   // 200705 (sentinel at 200704)
#define FOFF_B_N (BB_BINS * 512 + 1)         // 100353
#define TOTSLOT  (2 * N_EDGES)
#define PART_SLOTS (FB_BINS * 512 * NSH)     // 200704 partial rows (bf16, 128B each)
#define PASSA_WGS (((N_ITEMS + 31) / 32) * 8) // 1563*8: x&7 -> (shard=x>>1, halfblk=x&1)
#define PASSB_WGS ((N_ITEMS + 7) / 8)        // 6250
#define BWD_WGS ((N_USERS + 31) / 32)        // 3125

// ---- bf16 pack/unpack helpers --------------------------------------------
__device__ __forceinline__ float blo(unsigned u) {
    union { unsigned i; float f; } c; c.i = u << 16; return c.f;
}
__device__ __forceinline__ float bhi(unsigned u) {
    union { unsigned i; float f; } c; c.i = u & 0xFFFF0000u; return c.f;
}
__device__ __forceinline__ unsigned bpack(float x, float y) {
    __hip_bfloat16 a = __float2bfloat16(x), b = __float2bfloat16(y);
    unsigned short ua = *reinterpret_cast<unsigned short*>(&a);
    unsigned short ub = *reinterpret_cast<unsigned short*>(&b);
    return (unsigned)ua | ((unsigned)ub << 16);
}

// ---------------------------------------------------------------------------
// h2b: h_user fp32 -> packed bf16 pairs (hu16): one uint = features 2q,2q+1.
// ---------------------------------------------------------------------------
__global__ __launch_bounds__(256) void h2b_kernel(
    const float2* __restrict__ in, unsigned* __restrict__ out, int n) {
    int stride = gridDim.x * blockDim.x;
    for (int i = blockIdx.x * blockDim.x + threadIdx.x; i < n; i += stride) {
        float2 v = in[i];
        out[i] = bpack(v.x, v.y);
    }
}

// ---------------------------------------------------------------------------
// Histogram of coarse-bin sizes (294 bins, LDS-staged; NO global fine atomics).
// ---------------------------------------------------------------------------
__global__ __launch_bounds__(256) void hist_kernel(
    const int* __restrict__ src, const int* __restrict__ dst, int* __restrict__ gh) {
    __shared__ int h[NBINS];
    for (int i = threadIdx.x; i < NBINS; i += 256) h[i] = 0;
    __syncthreads();
    int stride = gridDim.x * blockDim.x;
    for (int e = blockIdx.x * blockDim.x + threadIdx.x; e < N_EDGES; e += stride) {
        atomicAdd(&h[dst[e] >> 9], 1);
        atomicAdd(&h[FB_BINS + (src[e] >> 9)], 1);
    }
    __syncthreads();
    for (int i = threadIdx.x; i < NBINS; i += 256) {
        int v = h[i];
        if (v) atomicAdd(&gh[i], v);
    }
}

// ---------------------------------------------------------------------------
// Single-block exclusive scan; also initializes the running cursor array.
// ---------------------------------------------------------------------------
__global__ void scan_excl(const int* __restrict__ in, int* __restrict__ out,
                          int* __restrict__ cur, int n) {
    const int T = 1024, E = 4;
    __shared__ int wsum[16];
    __shared__ int s_carry;
    if (threadIdx.x == 0) s_carry = 0;
    __syncthreads();

    int lane = threadIdx.x & 63;
    int wid  = threadIdx.x >> 6;

    for (int base = 0; base < n; base += T * E) {
        int idx0 = base + threadIdx.x * E;
        int v[E];
        int tot = 0;
#pragma unroll
        for (int e = 0; e < E; e++) {
            int i = idx0 + e;
            v[e] = (i < n) ? in[i] : 0;
            tot += v[e];
        }
        int incl = tot;
#pragma unroll
        for (int off = 1; off < 64; off <<= 1) {
            int t = __shfl_up(incl, off);
            if (lane >= off) incl += t;
        }
        if (lane == 63) wsum[wid] = incl;
        __syncthreads();
        if (wid == 0 && lane < 16) {
            int t = wsum[lane];
            int sc = t;
#pragma unroll
            for (int off = 1; off < 16; off <<= 1) {
                int u = __shfl_up(sc, off);
                if (lane >= off) sc += u;
            }
            wsum[lane] = sc - t;
        }
        __syncthreads();
        int wave_off = wsum[wid];
        int excl = s_carry + wave_off + incl - tot;
#pragma unroll
        for (int e = 0; e < E; e++) {
            int i = idx0 + e;
            if (i < n) { out[i] = excl; cur[i] = excl; }
            excl += v[e];
        }
        __syncthreads();
        if (threadIdx.x == T - 1) s_carry += wave_off + incl;
        __syncthreads();
    }
    if (threadIdx.x == 0) out[n] = s_carry;
}

// ---------------------------------------------------------------------------
// binfill: chunk-aggregated scatter into coarse bins (dense runs, L2-merged).
// fwd entry: s(17b) | d_local9<<17 ; bwd entry: d(16b) | s_local9<<16.
// ---------------------------------------------------------------------------
__global__ __launch_bounds__(256) void binfill_kernel(
    const int* __restrict__ src, const int* __restrict__ dst,
    int* __restrict__ gcur, unsigned* __restrict__ stage) {
    __shared__ int cnt[NBINS];
    __shared__ int gbase[NBINS];
    __shared__ int lcur[NBINS];
    int c = blockIdx.x;
    int base = c * CHUNK;
    int nEdge = N_EDGES - base; if (nEdge > CHUNK) nEdge = CHUNK;

    for (int t = threadIdx.x; t < NBINS; t += 256) { cnt[t] = 0; lcur[t] = 0; }
    __syncthreads();

    int es[8], ed[8];
#pragma unroll
    for (int j = 0; j < 8; j++) {
        int k = j * 256 + threadIdx.x;
        if (k < nEdge) {
            es[j] = src[base + k];
            ed[j] = dst[base + k];
            atomicAdd(&cnt[ed[j] >> 9], 1);
            atomicAdd(&cnt[FB_BINS + (es[j] >> 9)], 1);
        } else {
            es[j] = -1;
        }
    }
    __syncthreads();
    for (int t = threadIdx.x; t < NBINS; t += 256) {
        int cv = cnt[t];
        gbase[t] = cv ? atomicAdd(&gcur[t], cv) : 0;
    }
    __syncthreads();
#pragma unroll
    for (int j = 0; j < 8; j++) {
        if (es[j] >= 0) {
            int s = es[j], d = ed[j];
            int bf = d >> 9;
            int p = atomicAdd(&lcur[bf], 1);
            stage[gbase[bf] + p] = (unsigned)s | ((unsigned)(d & 511) << 17);
            int bb = FB_BINS + (s >> 9);
            int q = atomicAdd(&lcur[bb], 1);
            stage[gbase[bb] + q] = (unsigned)d | ((unsigned)(s & 511) << 16);
        }
    }
}

// ---------------------------------------------------------------------------
// redist3: balanced fine counting-sort, 196 WGs (one CU round), all-LDS.
// WG 0..97: one fwd bin, fine key = (item_local, user&3) -> 2048 counters.
// WG 98..195: two bwd bins sequentially, fine key = user_local -> 512 counters.
// Writes fine offsets + scattered stage2 (payload = bare gather index).
// ---------------------------------------------------------------------------
__global__ __launch_bounds__(512) void redist3_kernel(
    const unsigned* __restrict__ stage, const int* __restrict__ binoff,
    unsigned* __restrict__ stage2, int* __restrict__ foff_f, int* __restrict__ foff_b) {
    __shared__ int cnt[512 * NSH];
    __shared__ int wsum[8];
    int wg = blockIdx.x, t = threadIdx.x, lane = t & 63, wv = t >> 6;

    if (wg < FB_BINS) {
        int B = wg;
        int beg = binoff[B], end = binoff[B + 1];
        for (int j = t; j < 512 * NSH; j += 512) cnt[j] = 0;
        __syncthreads();
        for (int k = beg + t; k < end; k += 512) {
            unsigned e = stage[k];
            atomicAdd(&cnt[(((e >> 17) & 511) << 2) | (e & 3)], 1);
        }
        __syncthreads();
        int c[NSH]; int tot = 0;
#pragma unroll
        for (int j = 0; j < NSH; j++) { c[j] = cnt[(t << 2) | j]; tot += c[j]; }
        int incl = tot;
#pragma unroll
        for (int off = 1; off < 64; off <<= 1) {
            int u = __shfl_up(incl, off);
            if (lane >= off) incl += u;
        }
        if (lane == 63) wsum[wv] = incl;
        __syncthreads();
        if (t == 0) {
            int run = 0;
#pragma unroll
            for (int k2 = 0; k2 < 8; k2++) { int x = wsum[k2]; wsum[k2] = run; run += x; }
        }
        __syncthreads();
        int base = beg + wsum[wv] + incl - tot;
        int slot0 = (((B << 9) | t) << 2);
#pragma unroll
        for (int j = 0; j < NSH; j++) {
            foff_f[slot0 + j] = base;
            cnt[(t << 2) | j] = base;
            base += c[j];
        }
        if (B == FB_BINS - 1 && t == 0) foff_f[FB_BINS * 512 * NSH] = end;
        __syncthreads();
        for (int k = beg + t; k < end; k += 512) {
            unsigned e = stage[k];
            int idx = (((e >> 17) & 511) << 2) | (e & 3);
            int p = atomicAdd(&cnt[idx], 1);
            stage2[p] = e & 0x1FFFFu;
        }
    } else {
        for (int pass = 0; pass < 2; pass++) {
            int B = FB_BINS + ((wg - FB_BINS) << 1) + pass;
            int beg = binoff[B], end = binoff[B + 1];
            cnt[t] = 0;
            __syncthreads();
            for (int k = beg + t; k < end; k += 512) {
                unsigned e = stage[k];
                atomicAdd(&cnt[(e >> 16) & 511], 1);
            }
            __syncthreads();
            int v = cnt[t];
            int incl = v;
#pragma unroll
            for (int off = 1; off < 64; off <<= 1) {
                int u = __shfl_up(incl, off);
                if (lane >= off) incl += u;
            }
            if (lane == 63) wsum[wv] = incl;
            __syncthreads();
            if (t == 0) {
                int run = 0;
#pragma unroll
                for (int k2 = 0; k2 < 8; k2++) { int x = wsum[k2]; wsum[k2] = run; run += x; }
            }
            __syncthreads();
            int base = beg + wsum[wv] + incl - v;
            foff_b[((B - FB_BINS) << 9) | t] = base;
            cnt[t] = base;
            if (B == NBINS - 1 && t == 0) foff_b[BB_BINS * 512] = end;
            __syncthreads();
            for (int k = beg + t; k < end; k += 512) {
                unsigned e = stage[k];
                int p = atomicAdd(&cnt[(e >> 16) & 511], 1);
                stage2[p] = e & 0xFFFFu;
            }
            __syncthreads();
        }
    }
}

// ---------------------------------------------------------------------------
// Global softmax stats over edge_w[N_ITEMS]: stats[0]=max, stats[1]=sum(exp(x-max))
// ---------------------------------------------------------------------------
__global__ void softmax_stats_kernel(const float* __restrict__ w, float* __restrict__ stats) {
    __shared__ float red[16];
    int tid = threadIdx.x, lane = tid & 63, wid = tid >> 6;

    float m = -INFINITY;
    for (int i = tid; i < N_ITEMS; i += 1024) m = fmaxf(m, w[i]);
#pragma unroll
    for (int off = 32; off; off >>= 1) m = fmaxf(m, __shfl_xor(m, off));
    if (lane == 0) red[wid] = m;
    __syncthreads();
    if (tid == 0) {
        float t = red[0];
        for (int k = 1; k < 16; k++) t = fmaxf(t, red[k]);
        red[0] = t;
    }
    __syncthreads();
    m = red[0];
    __syncthreads();

    float s = 0.f;
    for (int i = tid; i < N_ITEMS; i += 1024) s += expf(w[i] - m);
#pragma unroll
    for (int off = 32; off; off >>= 1) s += __shfl_xor(s, off);
    if (lane == 0) red[wid] = s;
    __syncthreads();
    if (tid == 0) {
        float t = 0.f;
        for (int k = 0; k < 16; k++) t += red[k];
        stats[0] = m;
        stats[1] = t;
    }
}

// ---------------------------------------------------------------------------
// passA fwd: sharded gather. blockIdx = ib*8 + x; shard = x>>1 (2 XCDs/shard),
// halfblk = x&1. Each XCD's hu16 working set = one 3.2MB shard slice -> L2-hot.
// Partial sums (bf16) written nontemporal to avoid evicting the slice.
// ---------------------------------------------------------------------------
__global__ __launch_bounds__(256) void passA_fwd_kernel(
    const unsigned* __restrict__ hu16, const unsigned* __restrict__ stage2,
    const int* __restrict__ foff_f, unsigned* __restrict__ part) {
    int tid = threadIdx.x, lane = tid & 63, wv = tid >> 6;
    int q = lane & 31, half = lane >> 5;
    int ib = blockIdx.x >> 3, x = blockIdx.x & 7;
    int sh = x >> 1, hb = x & 1;
    int i0 = ib * 32 + hb * 16;

    for (int il = wv; il < 16; il += 4) {
        int i = i0 + il;
        if (i >= N_ITEMS) break;
        int slot = (i << 2) | sh;
        int a = foff_f[slot], b = foff_f[slot + 1];
        float ax = 0.f, ay = 0.f;
        int k = a;
        for (; k + 8 <= b; k += 8) {
            int s0 = (int)__builtin_nontemporal_load(&stage2[k + half]);
            int s1 = (int)__builtin_nontemporal_load(&stage2[k + 2 + half]);
            int s2 = (int)__builtin_nontemporal_load(&stage2[k + 4 + half]);
            int s3 = (int)__builtin_nontemporal_load(&stage2[k + 6 + half]);
            unsigned u0 = hu16[(s0 << 5) + q];
            unsigned u1 = hu16[(s1 << 5) + q];
            unsigned u2 = hu16[(s2 << 5) + q];
            unsigned u3 = hu16[(s3 << 5) + q];
            ax += (blo(u0) + blo(u1)) + (blo(u2) + blo(u3));
            ay += (bhi(u0) + bhi(u1)) + (bhi(u2) + bhi(u3));
        }
        for (; k + 2 <= b; k += 2) {
            unsigned u = hu16[((int)__builtin_nontemporal_load(&stage2[k + half]) << 5) + q];
            ax += blo(u); ay += bhi(u);
        }
        if (k < b && half == 0) {
            unsigned u = hu16[((int)__builtin_nontemporal_load(&stage2[k]) << 5) + q];
            ax += blo(u); ay += bhi(u);
        }
        ax += __shfl_xor(ax, 32);
        ay += __shfl_xor(ay, 32);
        if (half == 0)
            __builtin_nontemporal_store(bpack(ax, ay), &part[((size_t)slot << 5) + q]);
    }
}

// ---------------------------------------------------------------------------
// passB fwd: reduce NSH partials per item + fused epilogue -> bf16 rst.
// Pure streaming (nt loads), half-wave per item.
// ---------------------------------------------------------------------------
__global__ __launch_bounds__(256) void passB_fwd_kernel(
    const unsigned* __restrict__ part, const float* __restrict__ pf,
    const float* __restrict__ edge_w, const int* __restrict__ foff_f,
    const float* __restrict__ stats, unsigned* __restrict__ rst16) {
    int tid = threadIdx.x, lane = tid & 63, wv = tid >> 6;
    int q = lane & 31, half = lane >> 5;
    int i = blockIdx.x * 8 + wv * 2 + half;
    if (i >= N_ITEMS) return;
    float m = stats[0], ssum = stats[1];
    float ax = 0.f, ay = 0.f;
#pragma unroll
    for (int s = 0; s < NSH; s++) {
        unsigned u = __builtin_nontemporal_load(&part[(((size_t)(i << 2) | s) << 5) + q]);
        ax += blo(u); ay += bhi(u);
    }
    int dg = foff_f[(i << 2) + 4] - foff_f[i << 2];
    float deg = dg < 1 ? 1.f : (float)dg;
    float sc = expf(edge_w[i] - m) / (ssum * deg);
    const float2* PF2 = (const float2*)pf;
    float2 pv = PF2[(size_t)i * 32 + q];
    float vx = (ax + 0.5f * tanhf(pv.x)) * sc;
    float vy = (ay + 0.5f * tanhf(pv.y)) * sc;
    rst16[(size_t)i * 32 + q] = bpack(vx, vy);
}

// ---------------------------------------------------------------------------
// pass2 bwd: pure gather over bf16 rst (6.4MB table); fp32 out with deg norm.
// ---------------------------------------------------------------------------
__global__ __launch_bounds__(256) void pass2_bwd_kernel(
    const unsigned* __restrict__ rst16, const unsigned* __restrict__ stage2,
    const int* __restrict__ foff_b, float* __restrict__ out) {
    int tid = threadIdx.x, lane = tid & 63, wv = tid >> 6;
    int q = lane & 31, half = lane >> 5;
    float2* OUT2 = (float2*)out;
    int u0i = blockIdx.x * 32;

    for (int il = wv; il < 32; il += 4) {
        int u = u0i + il;
        if (u >= N_USERS) break;
        int a = foff_b[u], b = foff_b[u + 1];
        float ax = 0.f, ay = 0.f;
        int k = a;
        for (; k + 8 <= b; k += 8) {
            int d0 = (int)__builtin_nontemporal_load(&stage2[k + half]);
            int d1 = (int)__builtin_nontemporal_load(&stage2[k + 2 + half]);
            int d2 = (int)__builtin_nontemporal_load(&stage2[k + 4 + half]);
            int d3 = (int)__builtin_nontemporal_load(&stage2[k + 6 + half]);
            unsigned u0 = rst16[(d0 << 5) + q];
            unsigned u1 = rst16[(d1 << 5) + q];
            unsigned u2 = rst16[(d2 << 5) + q];
            unsigned u3 = rst16[(d3 << 5) + q];
            ax += (blo(u0) + blo(u1)) + (blo(u2) + blo(u3));
            ay += (bhi(u0) + bhi(u1)) + (bhi(u2) + bhi(u3));
        }
        for (; k + 2 <= b; k += 2) {
            unsigned e = rst16[((int)__builtin_nontemporal_load(&stage2[k + half]) << 5) + q];
            ax += blo(e); ay += bhi(e);
        }
        if (k < b && half == 0) {
            unsigned e = rst16[((int)__builtin_nontemporal_load(&stage2[k]) << 5) + q];
            ax += blo(e); ay += bhi(e);
        }
        ax += __shfl_xor(ax, 32);
        ay += __shfl_xor(ay, 32);
        if (half == 0) {
            float deg = (float)(b - a);
            if (deg < 1.f) deg = 1.f;
            OUT2[(size_t)u * 32 + q] = make_float2(ax / deg, ay / deg);
        }
    }
}

// ---------------------------------------------------------------------------
extern "C" void kernel_launch(void* const* d_in, const int* in_sizes, int n_in,
                              void* d_out, int out_size, void* d_ws, size_t ws_size,
                              hipStream_t stream) {
    const float* h_user = (const float*)d_in[0];   // [N_USERS, D]
    const float* pf     = (const float*)d_in[1];   // [N_ITEMS, D]
    const float* edge_w = (const float*)d_in[2];   // [N_ITEMS]
    const int*   src    = (const int*)d_in[3];     // [N_EDGES]
    const int*   dst    = (const int*)d_in[4];     // [N_EDGES]
    float* out = (float*)d_out;                    // [N_USERS, D]

    // workspace carve-up (~62 MB). part (25.7MB) aliases stage (16MB): stage is
    // dead after redist3, before passA writes part.
    char* p = (char*)d_ws;
    int* gh      = (int*)p;     p += sizeof(int) * NBINS;
    int* binoff  = (int*)p;     p += sizeof(int) * (NBINS + 1);
    int* gcur    = (int*)p;     p += sizeof(int) * NBINS;
    int* foff_f  = (int*)p;     p += sizeof(int) * FOFF_F_N;
    int* foff_b  = (int*)p;     p += sizeof(int) * FOFF_B_N;
    float* stats = (float*)p;   p += 4 * sizeof(float);
    unsigned* part  = (unsigned*)p;
    unsigned* stage = part;                         // alias (see above)
    p += sizeof(unsigned) * (size_t)PART_SLOTS * 32;
    unsigned* stage2 = (unsigned*)p; p += sizeof(unsigned) * (size_t)TOTSLOT;
    unsigned* hu16   = (unsigned*)p; p += sizeof(unsigned) * (size_t)N_USERS * 32;
    unsigned* rst16  = (unsigned*)p; p += sizeof(unsigned) * (size_t)N_ITEMS * 32;

    hipMemsetAsync(gh, 0, sizeof(int) * NBINS, stream);

    hist_kernel<<<256, 256, 0, stream>>>(src, dst, gh);
    scan_excl<<<1, 1024, 0, stream>>>(gh, binoff, gcur, NBINS);
    binfill_kernel<<<NCHUNK, 256, 0, stream>>>(src, dst, gcur, stage);
    redist3_kernel<<<196, 512, 0, stream>>>(stage, binoff, stage2, foff_f, foff_b);
    h2b_kernel<<<1024, 256, 0, stream>>>((const float2*)h_user, hu16, N_USERS * 32);
    softmax_stats_kernel<<<1, 1024, 0, stream>>>(edge_w, stats);
    passA_fwd_kernel<<<PASSA_WGS, 256, 0, stream>>>(hu16, stage2, foff_f, part);
    passB_fwd_kernel<<<PASSB_WGS, 256, 0, stream>>>(part, pf, edge_w, foff_f, stats, rst16);
    pass2_bwd_kernel<<<BWD_WGS, 256, 0, stream>>>(rst16, stage2, foff_b, out);
}

// Round 5
// 344.275 us; speedup vs baseline: 1.5352x; 1.1563x over previous
//
#include <hip/hip_runtime.h>
#include <hip/hip_bf16.h>
#include <math.h>

#define N_USERS 100000
#define N_ITEMS 50000
#define N_EDGES 2000000
#define D 64

// Coarse bins: 512 nodes per bin (binfill write-coalescing granularity).
#define FB_BINS 98                    // ceil(50000/512)  forward (by item)
#define BB_BINS 196                   // ceil(100000/512) backward (by user)
#define NBINS   (FB_BINS + BB_BINS)   // 294
#define CHUNK   2048                  // edges per binfill WG
#define NCHUNK  ((N_EDGES + CHUNK - 1) / CHUNK)   // 977
#define FOFF_F_N (FB_BINS * 512 + 1)  // 50177
#define FOFF_B_N (BB_BINS * 512 + 1)  // 100353
#define TOTSLOT  (2 * N_EDGES)
// gathers: 256-thr WGs, 4 waves, 4 nodes per wave = 16 nodes per WG.
#define FWD_WGS (N_ITEMS / 16)        // 3125
#define BWD_WGS ((N_USERS + 15) / 16) // 6250

// ---- bf16 pack/unpack helpers --------------------------------------------
__device__ __forceinline__ float blo(unsigned u) {
    union { unsigned i; float f; } c; c.i = u << 16; return c.f;
}
__device__ __forceinline__ float bhi(unsigned u) {
    union { unsigned i; float f; } c; c.i = u & 0xFFFF0000u; return c.f;
}
__device__ __forceinline__ unsigned bpack(float x, float y) {
    __hip_bfloat16 a = __float2bfloat16(x), b = __float2bfloat16(y);
    unsigned short ua = *reinterpret_cast<unsigned short*>(&a);
    unsigned short ub = *reinterpret_cast<unsigned short*>(&b);
    return (unsigned)ua | ((unsigned)ub << 16);
}

// ---------------------------------------------------------------------------
// prep: fused h2b (fp32 -> packed bf16 pairs) + coarse LDS histogram.
// Two independent grid-stride loops; no global fine atomics (R3 lesson).
// ---------------------------------------------------------------------------
__global__ __launch_bounds__(256) void prep_kernel(
    const float2* __restrict__ hin, unsigned* __restrict__ hu16,
    const int* __restrict__ src, const int* __restrict__ dst,
    int* __restrict__ gh) {
    __shared__ int h[NBINS];
    for (int i = threadIdx.x; i < NBINS; i += 256) h[i] = 0;
    __syncthreads();
    int stride = gridDim.x * blockDim.x;
    int t0 = blockIdx.x * blockDim.x + threadIdx.x;
    for (int i = t0; i < N_USERS * 32; i += stride) {
        float2 v = hin[i];
        hu16[i] = bpack(v.x, v.y);
    }
    for (int e = t0; e < N_EDGES; e += stride) {
        atomicAdd(&h[dst[e] >> 9], 1);
        atomicAdd(&h[FB_BINS + (src[e] >> 9)], 1);
    }
    __syncthreads();
    for (int i = threadIdx.x; i < NBINS; i += 256) {
        int v = h[i];
        if (v) atomicAdd(&gh[i], v);
    }
}

// ---------------------------------------------------------------------------
// scan_soft: block 0 = exclusive scan of 294 coarse bins (-> binoff, gcur);
// block 1 = softmax stats over edge_w (stats[0]=max, stats[1]=sum exp).
// ---------------------------------------------------------------------------
__global__ void scan_soft_kernel(const int* __restrict__ in, int* __restrict__ out,
                                 int* __restrict__ cur,
                                 const float* __restrict__ w, float* __restrict__ stats) {
    __shared__ float redf[16];
    __shared__ int wsum[16];
    int tid = threadIdx.x, lane = tid & 63, wid = tid >> 6;

    if (blockIdx.x == 0) {
        // n = NBINS fits in one 1024x4 tile
        int idx0 = tid * 4;
        int v[4]; int tot = 0;
#pragma unroll
        for (int e = 0; e < 4; e++) {
            int i = idx0 + e;
            v[e] = (i < NBINS) ? in[i] : 0;
            tot += v[e];
        }
        int incl = tot;
#pragma unroll
        for (int off = 1; off < 64; off <<= 1) {
            int t = __shfl_up(incl, off);
            if (lane >= off) incl += t;
        }
        if (lane == 63) wsum[wid] = incl;
        __syncthreads();
        if (wid == 0 && lane < 16) {
            int t = wsum[lane];
            int sc = t;
#pragma unroll
            for (int off = 1; off < 16; off <<= 1) {
                int u = __shfl_up(sc, off);
                if (lane >= off) sc += u;
            }
            wsum[lane] = sc - t;
        }
        __syncthreads();
        int excl = wsum[wid] + incl - tot;
#pragma unroll
        for (int e = 0; e < 4; e++) {
            int i = idx0 + e;
            if (i < NBINS) { out[i] = excl; cur[i] = excl; }
            if (i == NBINS) out[i] = excl;
            excl += v[e];
        }
        if (tid == 1023) out[NBINS] = excl;  // safety (covered above too)
        return;
    }

    float m = -INFINITY;
    for (int i = tid; i < N_ITEMS; i += 1024) m = fmaxf(m, w[i]);
#pragma unroll
    for (int off = 32; off; off >>= 1) m = fmaxf(m, __shfl_xor(m, off));
    if (lane == 0) redf[wid] = m;
    __syncthreads();
    if (tid == 0) {
        float t = redf[0];
        for (int k = 1; k < 16; k++) t = fmaxf(t, redf[k]);
        redf[0] = t;
    }
    __syncthreads();
    m = redf[0];
    __syncthreads();

    float s = 0.f;
    for (int i = tid; i < N_ITEMS; i += 1024) s += expf(w[i] - m);
#pragma unroll
    for (int off = 32; off; off >>= 1) s += __shfl_xor(s, off);
    if (lane == 0) redf[wid] = s;
    __syncthreads();
    if (tid == 0) {
        float t = 0.f;
        for (int k = 0; k < 16; k++) t += redf[k];
        stats[0] = m;
        stats[1] = t;
    }
}

// ---------------------------------------------------------------------------
// binfill: chunk-aggregated scatter into coarse bins (dense runs, L2-merged).
// fwd entry: s(17b) | d_local9<<17 ; bwd entry: d(16b) | s_local9<<16.
// ---------------------------------------------------------------------------
__global__ __launch_bounds__(256) void binfill_kernel(
    const int* __restrict__ src, const int* __restrict__ dst,
    int* __restrict__ gcur, unsigned* __restrict__ stage) {
    __shared__ int cnt[NBINS];
    __shared__ int gbase[NBINS];
    __shared__ int lcur[NBINS];
    int c = blockIdx.x;
    int base = c * CHUNK;
    int nEdge = N_EDGES - base; if (nEdge > CHUNK) nEdge = CHUNK;

    for (int t = threadIdx.x; t < NBINS; t += 256) { cnt[t] = 0; lcur[t] = 0; }
    __syncthreads();

    int es[8], ed[8];
#pragma unroll
    for (int j = 0; j < 8; j++) {
        int k = j * 256 + threadIdx.x;
        if (k < nEdge) {
            es[j] = src[base + k];
            ed[j] = dst[base + k];
            atomicAdd(&cnt[ed[j] >> 9], 1);
            atomicAdd(&cnt[FB_BINS + (es[j] >> 9)], 1);
        } else {
            es[j] = -1;
        }
    }
    __syncthreads();
    for (int t = threadIdx.x; t < NBINS; t += 256) {
        int cv = cnt[t];
        gbase[t] = cv ? atomicAdd(&gcur[t], cv) : 0;
    }
    __syncthreads();
#pragma unroll
    for (int j = 0; j < 8; j++) {
        if (es[j] >= 0) {
            int s = es[j], d = ed[j];
            int bf = d >> 9;
            int p = atomicAdd(&lcur[bf], 1);
            stage[gbase[bf] + p] = (unsigned)s | ((unsigned)(d & 511) << 17);
            int bb = FB_BINS + (s >> 9);
            int q = atomicAdd(&lcur[bb], 1);
            stage[gbase[bb] + q] = (unsigned)d | ((unsigned)(s & 511) << 16);
        }
    }
}

// ---------------------------------------------------------------------------
// redist3: balanced fine counting-sort, 196 WGs (one CU round), all-LDS.
// WG 0..97: one fwd bin (~20.5K edges); WG 98..195: two bwd bins (2x ~10.2K).
// Fine key = 9-bit local node id. stage2 payload = bare gather index.
// ---------------------------------------------------------------------------
__global__ __launch_bounds__(512) void redist3_kernel(
    const unsigned* __restrict__ stage, const int* __restrict__ binoff,
    unsigned* __restrict__ stage2, int* __restrict__ foff_f, int* __restrict__ foff_b) {
    __shared__ int cnt[512];
    __shared__ int wsum[8];
    int wg = blockIdx.x, t = threadIdx.x, lane = t & 63, wv = t >> 6;

    if (wg < FB_BINS) {
        int B = wg;
        int beg = binoff[B], end = binoff[B + 1];
        cnt[t] = 0;
        __syncthreads();
        for (int k = beg + t; k < end; k += 512) {
            unsigned e = stage[k];
            atomicAdd(&cnt[(e >> 17) & 511], 1);
        }
        __syncthreads();
        int v = cnt[t];
        int incl = v;
#pragma unroll
        for (int off = 1; off < 64; off <<= 1) {
            int u = __shfl_up(incl, off);
            if (lane >= off) incl += u;
        }
        if (lane == 63) wsum[wv] = incl;
        __syncthreads();
        if (t == 0) {
            int run = 0;
#pragma unroll
            for (int k2 = 0; k2 < 8; k2++) { int x = wsum[k2]; wsum[k2] = run; run += x; }
        }
        __syncthreads();
        int base = beg + wsum[wv] + incl - v;
        foff_f[(B << 9) | t] = base;
        cnt[t] = base;
        if (B == FB_BINS - 1 && t == 0) foff_f[FB_BINS * 512] = end;
        __syncthreads();
        for (int k = beg + t; k < end; k += 512) {
            unsigned e = stage[k];
            int p = atomicAdd(&cnt[(e >> 17) & 511], 1);
            stage2[p] = e & 0x1FFFFu;
        }
    } else {
        for (int pass = 0; pass < 2; pass++) {
            int B = FB_BINS + ((wg - FB_BINS) << 1) + pass;
            int beg = binoff[B], end = binoff[B + 1];
            cnt[t] = 0;
            __syncthreads();
            for (int k = beg + t; k < end; k += 512) {
                unsigned e = stage[k];
                atomicAdd(&cnt[(e >> 16) & 511], 1);
            }
            __syncthreads();
            int v = cnt[t];
            int incl = v;
#pragma unroll
            for (int off = 1; off < 64; off <<= 1) {
                int u = __shfl_up(incl, off);
                if (lane >= off) incl += u;
            }
            if (lane == 63) wsum[wv] = incl;
            __syncthreads();
            if (t == 0) {
                int run = 0;
#pragma unroll
                for (int k2 = 0; k2 < 8; k2++) { int x = wsum[k2]; wsum[k2] = run; run += x; }
            }
            __syncthreads();
            int base = beg + wsum[wv] + incl - v;
            foff_b[((B - FB_BINS) << 9) | t] = base;
            cnt[t] = base;
            if (B == NBINS - 1 && t == 0) foff_b[BB_BINS * 512] = end;
            __syncthreads();
            for (int k = beg + t; k < end; k += 512) {
                unsigned e = stage[k];
                int p = atomicAdd(&cnt[(e >> 16) & 511], 1);
                stage2[p] = e & 0xFFFFu;
            }
            __syncthreads();
        }
    }
}

// ---------------------------------------------------------------------------
// fwd_gather: pure gather, 16 items per 256-thr WG (4 per wave), 16-edge
// unrolled inner loop = 8 independent row-loads in flight per lane (MLP for
// the latency-bound regime). Fused epilogue -> bf16 rst.
// ---------------------------------------------------------------------------
__global__ __launch_bounds__(256) void fwd_gather_kernel(
    const unsigned* __restrict__ hu16, const float* __restrict__ pf,
    const float* __restrict__ edge_w, const unsigned* __restrict__ stage2,
    const int* __restrict__ foff_f, const float* __restrict__ stats,
    unsigned* __restrict__ rst16) {
    int tid = threadIdx.x, lane = tid & 63, wv = tid >> 6;
    int q = lane & 31, half = lane >> 5;
    float m = stats[0], ssum = stats[1];
    const float2* PF2 = (const float2*)pf;
    int i0 = blockIdx.x * 16;

    for (int il = wv; il < 16; il += 4) {
        int i = i0 + il;
        if (i >= N_ITEMS) break;
        int a = foff_f[i], b = foff_f[i + 1];
        float ax = 0.f, ay = 0.f;
        int k = a;
        for (; k + 16 <= b; k += 16) {
            int s0 = (int)__builtin_nontemporal_load(&stage2[k + half]);
            int s1 = (int)__builtin_nontemporal_load(&stage2[k + 2 + half]);
            int s2 = (int)__builtin_nontemporal_load(&stage2[k + 4 + half]);
            int s3 = (int)__builtin_nontemporal_load(&stage2[k + 6 + half]);
            int s4 = (int)__builtin_nontemporal_load(&stage2[k + 8 + half]);
            int s5 = (int)__builtin_nontemporal_load(&stage2[k + 10 + half]);
            int s6 = (int)__builtin_nontemporal_load(&stage2[k + 12 + half]);
            int s7 = (int)__builtin_nontemporal_load(&stage2[k + 14 + half]);
            unsigned u0 = hu16[(s0 << 5) + q];
            unsigned u1 = hu16[(s1 << 5) + q];
            unsigned u2 = hu16[(s2 << 5) + q];
            unsigned u3 = hu16[(s3 << 5) + q];
            unsigned u4 = hu16[(s4 << 5) + q];
            unsigned u5 = hu16[(s5 << 5) + q];
            unsigned u6 = hu16[(s6 << 5) + q];
            unsigned u7 = hu16[(s7 << 5) + q];
            ax += ((blo(u0) + blo(u1)) + (blo(u2) + blo(u3)))
                + ((blo(u4) + blo(u5)) + (blo(u6) + blo(u7)));
            ay += ((bhi(u0) + bhi(u1)) + (bhi(u2) + bhi(u3)))
                + ((bhi(u4) + bhi(u5)) + (bhi(u6) + bhi(u7)));
        }
        if (k + 8 <= b) {
            int s0 = (int)__builtin_nontemporal_load(&stage2[k + half]);
            int s1 = (int)__builtin_nontemporal_load(&stage2[k + 2 + half]);
            int s2 = (int)__builtin_nontemporal_load(&stage2[k + 4 + half]);
            int s3 = (int)__builtin_nontemporal_load(&stage2[k + 6 + half]);
            unsigned u0 = hu16[(s0 << 5) + q];
            unsigned u1 = hu16[(s1 << 5) + q];
            unsigned u2 = hu16[(s2 << 5) + q];
            unsigned u3 = hu16[(s3 << 5) + q];
            ax += (blo(u0) + blo(u1)) + (blo(u2) + blo(u3));
            ay += (bhi(u0) + bhi(u1)) + (bhi(u2) + bhi(u3));
            k += 8;
        }
        for (; k + 2 <= b; k += 2) {
            unsigned u = hu16[((int)__builtin_nontemporal_load(&stage2[k + half]) << 5) + q];
            ax += blo(u); ay += bhi(u);
        }
        if (k < b && half == 0) {
            unsigned u = hu16[((int)__builtin_nontemporal_load(&stage2[k]) << 5) + q];
            ax += blo(u); ay += bhi(u);
        }
        ax += __shfl_xor(ax, 32);
        ay += __shfl_xor(ay, 32);
        if (half == 0) {
            float deg = (float)(b - a);
            if (deg < 1.f) deg = 1.f;
            float sc = expf(edge_w[i] - m) / (ssum * deg);
            float2 pv = PF2[(size_t)i * 32 + q];
            float vx = (ax + 0.5f * tanhf(pv.x)) * sc;
            float vy = (ay + 0.5f * tanhf(pv.y)) * sc;
            rst16[(size_t)i * 32 + q] = bpack(vx, vy);
        }
    }
}

// ---------------------------------------------------------------------------
// bwd_gather: same plan over bf16 rst (6.4MB table); fp32 out with deg norm.
// ---------------------------------------------------------------------------
__global__ __launch_bounds__(256) void bwd_gather_kernel(
    const unsigned* __restrict__ rst16, const unsigned* __restrict__ stage2,
    const int* __restrict__ foff_b, float* __restrict__ out) {
    int tid = threadIdx.x, lane = tid & 63, wv = tid >> 6;
    int q = lane & 31, half = lane >> 5;
    float2* OUT2 = (float2*)out;
    int u0i = blockIdx.x * 16;

    for (int il = wv; il < 16; il += 4) {
        int u = u0i + il;
        if (u >= N_USERS) break;
        int a = foff_b[u], b = foff_b[u + 1];
        float ax = 0.f, ay = 0.f;
        int k = a;
        for (; k + 16 <= b; k += 16) {
            int d0 = (int)__builtin_nontemporal_load(&stage2[k + half]);
            int d1 = (int)__builtin_nontemporal_load(&stage2[k + 2 + half]);
            int d2 = (int)__builtin_nontemporal_load(&stage2[k + 4 + half]);
            int d3 = (int)__builtin_nontemporal_load(&stage2[k + 6 + half]);
            int d4 = (int)__builtin_nontemporal_load(&stage2[k + 8 + half]);
            int d5 = (int)__builtin_nontemporal_load(&stage2[k + 10 + half]);
            int d6 = (int)__builtin_nontemporal_load(&stage2[k + 12 + half]);
            int d7 = (int)__builtin_nontemporal_load(&stage2[k + 14 + half]);
            unsigned u0 = rst16[(d0 << 5) + q];
            unsigned u1 = rst16[(d1 << 5) + q];
            unsigned u2 = rst16[(d2 << 5) + q];
            unsigned u3 = rst16[(d3 << 5) + q];
            unsigned u4 = rst16[(d4 << 5) + q];
            unsigned u5 = rst16[(d5 << 5) + q];
            unsigned u6 = rst16[(d6 << 5) + q];
            unsigned u7 = rst16[(d7 << 5) + q];
            ax += ((blo(u0) + blo(u1)) + (blo(u2) + blo(u3)))
                + ((blo(u4) + blo(u5)) + (blo(u6) + blo(u7)));
            ay += ((bhi(u0) + bhi(u1)) + (bhi(u2) + bhi(u3)))
                + ((bhi(u4) + bhi(u5)) + (bhi(u6) + bhi(u7)));
        }
        if (k + 8 <= b) {
            int d0 = (int)__builtin_nontemporal_load(&stage2[k + half]);
            int d1 = (int)__builtin_nontemporal_load(&stage2[k + 2 + half]);
            int d2 = (int)__builtin_nontemporal_load(&stage2[k + 4 + half]);
            int d3 = (int)__builtin_nontemporal_load(&stage2[k + 6 + half]);
            unsigned u0 = rst16[(d0 << 5) + q];
            unsigned u1 = rst16[(d1 << 5) + q];
            unsigned u2 = rst16[(d2 << 5) + q];
            unsigned u3 = rst16[(d3 << 5) + q];
            ax += (blo(u0) + blo(u1)) + (blo(u2) + blo(u3));
            ay += (bhi(u0) + bhi(u1)) + (bhi(u2) + bhi(u3));
            k += 8;
        }
        for (; k + 2 <= b; k += 2) {
            unsigned e = rst16[((int)__builtin_nontemporal_load(&stage2[k + half]) << 5) + q];
            ax += blo(e); ay += bhi(e);
        }
        if (k < b && half == 0) {
            unsigned e = rst16[((int)__builtin_nontemporal_load(&stage2[k]) << 5) + q];
            ax += blo(e); ay += bhi(e);
        }
        ax += __shfl_xor(ax, 32);
        ay += __shfl_xor(ay, 32);
        if (half == 0) {
            float deg = (float)(b - a);
            if (deg < 1.f) deg = 1.f;
            OUT2[(size_t)u * 32 + q] = make_float2(ax / deg, ay / deg);
        }
    }
}

// ---------------------------------------------------------------------------
extern "C" void kernel_launch(void* const* d_in, const int* in_sizes, int n_in,
                              void* d_out, int out_size, void* d_ws, size_t ws_size,
                              hipStream_t stream) {
    const float* h_user = (const float*)d_in[0];   // [N_USERS, D]
    const float* pf     = (const float*)d_in[1];   // [N_ITEMS, D]
    const float* edge_w = (const float*)d_in[2];   // [N_ITEMS]
    const int*   src    = (const int*)d_in[3];     // [N_EDGES]
    const int*   dst    = (const int*)d_in[4];     // [N_EDGES]
    float* out = (float*)d_out;                    // [N_USERS, D]

    // workspace carve-up (~52 MB)
    char* p = (char*)d_ws;
    int* gh      = (int*)p;     p += sizeof(int) * NBINS;
    int* binoff  = (int*)p;     p += sizeof(int) * (NBINS + 1);
    int* gcur    = (int*)p;     p += sizeof(int) * NBINS;
    int* foff_f  = (int*)p;     p += sizeof(int) * FOFF_F_N;
    int* foff_b  = (int*)p;     p += sizeof(int) * FOFF_B_N;
    float* stats = (float*)p;   p += 4 * sizeof(float);
    unsigned* stage  = (unsigned*)p; p += sizeof(unsigned) * (size_t)TOTSLOT;
    unsigned* stage2 = (unsigned*)p; p += sizeof(unsigned) * (size_t)TOTSLOT;
    unsigned* hu16   = (unsigned*)p; p += sizeof(unsigned) * (size_t)N_USERS * 32;
    unsigned* rst16  = (unsigned*)p; p += sizeof(unsigned) * (size_t)N_ITEMS * 32;

    hipMemsetAsync(gh, 0, sizeof(int) * NBINS, stream);

    prep_kernel<<<1024, 256, 0, stream>>>((const float2*)h_user, hu16, src, dst, gh);
    scan_soft_kernel<<<2, 1024, 0, stream>>>(gh, binoff, gcur, edge_w, stats);
    binfill_kernel<<<NCHUNK, 256, 0, stream>>>(src, dst, gcur, stage);
    redist3_kernel<<<196, 512, 0, stream>>>(stage, binoff, stage2, foff_f, foff_b);
    fwd_gather_kernel<<<FWD_WGS, 256, 0, stream>>>(hu16, pf, edge_w, stage2, foff_f, stats, rst16);
    bwd_gather_kernel<<<BWD_WGS, 256, 0, stream>>>(rst16, stage2, foff_b, out);
}